// Round 6
// baseline (912.256 us; speedup 1.0000x reference)
//
#include <hip/hip_runtime.h>

#define MDIM 4096
#define KDIM 4096
#define NDIM 14336

typedef __attribute__((ext_vector_type(8))) short bf16x8;
typedef __attribute__((ext_vector_type(4))) short bf16x4;
typedef __attribute__((ext_vector_type(4))) float f32x4;

// round-to-nearest-even fp32 -> bf16
__device__ __forceinline__ unsigned short f2bf(float f) {
  unsigned u = __float_as_uint(f);
  return (unsigned short)((u + 0x7FFFu + ((u >> 16) & 1u)) >> 16);
}

// async 16B global -> LDS (lane i lands at ldsbase + i*16)
__device__ __forceinline__ void async_copy16(const void* g, void* l) {
  __builtin_amdgcn_global_load_lds((const __attribute__((address_space(1))) unsigned*)g,
                                   (__attribute__((address_space(3))) unsigned*)l, 16, 0, 0);
}

// inline-asm LDS read: escapes the compiler's conservative vmcnt drain between
// global_load_lds and a C++ LDS load. [rule 18: follow the lgkmcnt(0) wait with
// sched_barrier(0) before consuming MFMAs]
__device__ __forceinline__ bf16x8 ds_read_b128(const short* p) {
  bf16x8 r;
  auto lp = (const __attribute__((address_space(3))) short*)p;
  asm volatile("ds_read_b128 %0, %1" : "=v"(r) : "v"(lp));
  return r;
}

// ---------------- P1: X fp32 -> bf16 ----------------
__global__ __launch_bounds__(256) void cvt_x_kernel(const float* __restrict__ X,
                                                    short* __restrict__ Xb) {
  const int i = blockIdx.x * 256 + threadIdx.x;  // 8 floats per thread
  const float4* p = (const float4*)X + (size_t)i * 2;
  const float4 a = p[0], b = p[1];
  bf16x8 v;
  v[0] = f2bf(a.x); v[1] = f2bf(a.y); v[2] = f2bf(a.z); v[3] = f2bf(a.w);
  v[4] = f2bf(b.x); v[5] = f2bf(b.y); v[6] = f2bf(b.z); v[7] = f2bf(b.w);
  *((bf16x8*)Xb + i) = v;
}

// ---------------- P2: dequant Q[K][N] int32 -> Wt[N][K] bf16 (transposed) ----------------
constexpr int DQ_STRIDE = 264;  // 256 + 8 pad shorts; 16B-aligned rows
__global__ __launch_bounds__(512) void dequant_w_kernel(const int* __restrict__ Q,
                                                        const float* __restrict__ S,
                                                        short* __restrict__ Wt) {
  __shared__ short Ls[128 * DQ_STRIDE];  // [n][k]
  const int k0 = blockIdx.x * 256;
  const int n0 = blockIdx.y * 128;
  const int t  = threadIdx.x;

  const int n4  = (t & 31) * 4;   // 0..124
  const int rbi = (t >> 5) * 4;   // 0..60
#pragma unroll
  for (int kc = 0; kc < 4; ++kc) {
    const int g  = (k0 >> 6) + kc;  // GROUP == 64
    const int kb = k0 + kc * 64 + rbi;
    const float4 s4 = *(const float4*)(S + (size_t)g * NDIM + n0 + n4);
    int4 q[4];
#pragma unroll
    for (int i = 0; i < 4; ++i)
      q[i] = *(const int4*)(Q + (size_t)(kb + i) * NDIM + n0 + n4);
    short* lp = &Ls[n4 * DQ_STRIDE + kc * 64 + rbi];
    bf16x4 v;
    v[0] = (short)f2bf((float)(q[0].x - 8) * s4.x);
    v[1] = (short)f2bf((float)(q[1].x - 8) * s4.x);
    v[2] = (short)f2bf((float)(q[2].x - 8) * s4.x);
    v[3] = (short)f2bf((float)(q[3].x - 8) * s4.x);
    *(bf16x4*)(lp + 0 * DQ_STRIDE) = v;
    v[0] = (short)f2bf((float)(q[0].y - 8) * s4.y);
    v[1] = (short)f2bf((float)(q[1].y - 8) * s4.y);
    v[2] = (short)f2bf((float)(q[2].y - 8) * s4.y);
    v[3] = (short)f2bf((float)(q[3].y - 8) * s4.y);
    *(bf16x4*)(lp + 1 * DQ_STRIDE) = v;
    v[0] = (short)f2bf((float)(q[0].z - 8) * s4.z);
    v[1] = (short)f2bf((float)(q[1].z - 8) * s4.z);
    v[2] = (short)f2bf((float)(q[2].z - 8) * s4.z);
    v[3] = (short)f2bf((float)(q[3].z - 8) * s4.z);
    *(bf16x4*)(lp + 2 * DQ_STRIDE) = v;
    v[0] = (short)f2bf((float)(q[0].w - 8) * s4.w);
    v[1] = (short)f2bf((float)(q[1].w - 8) * s4.w);
    v[2] = (short)f2bf((float)(q[2].w - 8) * s4.w);
    v[3] = (short)f2bf((float)(q[3].w - 8) * s4.w);
    *(bf16x4*)(lp + 3 * DQ_STRIDE) = v;
  }
  __syncthreads();

  const int c = (t & 7) * 8;  // 0..56 shorts
#pragma unroll
  for (int p = 0; p < 2; ++p) {
    const int nr = (t >> 3) + p * 64;  // 0..127
    const short* lr = &Ls[nr * DQ_STRIDE + c];
    short* wp = Wt + (size_t)(n0 + nr) * KDIM + k0 + c;
#pragma unroll
    for (int r = 0; r < 4; ++r)
      *(bf16x8*)(wp + r * 64) = *(const bf16x8*)(lr + r * 64);
  }
}

// ---------------- GEMM v6: 256x256, per-phase barrier pairs (true 8-phase-style) ----------------
// 8 waves (2M x 4N, wave tile 128x64), BK=64, double-buffered 128 KiB LDS.
// Per K-tile kt: 4 phases, each {ds_read; stage 1 group of kt+1; s_barrier;
// lgkmcnt(0); sched_barrier; setprio(1); 16 MFMA; setprio(0); s_barrier}.
// Reads = minimum 24 b128/wave/tile: A k-half read once, held across 2 phases.
// vmcnt(2) once per tile at P0 (drains tile kt's 8 ops, keeps kt+1.g0 in
// flight; never 0 in the main loop). P0's reads follow the RAW barrier.
// Swizzle/fragment/epilogue algebra = verified v1 pattern (0 conflicts).
__global__ __launch_bounds__(512, 2)
void gemm_bf16tt(const short* __restrict__ Xb, const short* __restrict__ Wt,
                 float* __restrict__ Out) {
  __shared__ short As[2][256 * 64];  // 64 KiB
  __shared__ short Bs[2][256 * 64];  // 64 KiB

  const int bm = blockIdx.x * 256;  // 16 blocks
  const int bn = blockIdx.y * 256;  // 56 blocks
  const int tid = threadIdx.x, lane = tid & 63, wave = tid >> 6;
  const int wr = wave >> 2;   // 0..1  M half (128 rows)
  const int wc = wave & 3;    // 0..3  N quarter (64 cols)
  const int quad = lane >> 4, l16 = lane & 15;
  const int lx = l16 & 7;

  f32x4 acc[8][4];
#pragma unroll
  for (int i = 0; i < 8; ++i)
#pragma unroll
    for (int j = 0; j < 4; ++j) acc[i][j] = (f32x4){0.f, 0.f, 0.f, 0.f};

  // staging: thread covers row (tid>>3), slot tid&7; source k pre-swizzled
  const int row0 = tid >> 3;                        // 0..63
  const int kof  = ((tid & 7) ^ (row0 & 7)) * 8;
  const size_t aoff = (size_t)(bm + row0) * KDIM + kof;
  const size_t boff = (size_t)(bn + row0) * KDIM + kof;
  const int ldst_off = wave * 8 * 64;  // wave-uniform: 8 rows per wave per op

  // groups: 0 = A rows[0,128), 1 = A rows[128,256), 2 = B[0,128), 3 = B[128,256)
#define STAGE_G(buf, g, kt1)                                                          \
  do {                                                                                \
    const short* gsrc = (((g) < 2) ? (Xb + aoff) : (Wt + boff)) +                     \
                        (size_t)((g) & 1) * 128 * KDIM + (size_t)(kt1) * 64;          \
    short* ldst = (((g) < 2) ? As[buf] : Bs[buf]) + (((g) & 1) * 128) * 64 + ldst_off;\
    async_copy16(gsrc, ldst);                                                         \
    async_copy16(gsrc + (size_t)64 * KDIM, ldst + 64 * 64);                           \
  } while (0)

  // fragment reads (cur buffer): slot for k-half s is ((s*4+quad)^lx)*8 shorts
#define DSREAD_A(s)                                                                   \
  _Pragma("unroll") for (int i = 0; i < 8; ++i)                                       \
      af[i] = ds_read_b128(&Ab[(wr * 128 + i * 16 + l16) * 64 + (((s)*4 + quad) ^ lx) * 8]);
#define DSREAD_B(s, nh)                                                               \
  _Pragma("unroll") for (int j = 0; j < 2; ++j)                                       \
      bv[j] = ds_read_b128(&Bb[(wc * 64 + ((nh)*2 + j) * 16 + l16) * 64 + (((s)*4 + quad) ^ lx) * 8]);
#define MFMA16(nh)                                                                    \
  do {                                                                                \
    __builtin_amdgcn_s_setprio(1);                                                    \
    _Pragma("unroll") for (int i = 0; i < 8; ++i)                                     \
      _Pragma("unroll") for (int j = 0; j < 2; ++j)                                   \
        acc[i][(nh)*2 + j] = __builtin_amdgcn_mfma_f32_16x16x32_bf16(                 \
            af[i], bv[j], acc[i][(nh)*2 + j], 0, 0, 0);                               \
    __builtin_amdgcn_s_setprio(0);                                                    \
  } while (0)
#define WAIT_LGK()                                                                    \
  asm volatile("s_waitcnt lgkmcnt(0)" ::: "memory");                                  \
  __builtin_amdgcn_sched_barrier(0)
#define BAR()                                                                         \
  __builtin_amdgcn_s_barrier();                                                       \
  __builtin_amdgcn_sched_barrier(0)

  constexpr int NT = KDIM / 64;  // 64

  // prologue: stage all 4 groups of tile 0 into buf 0 (8 vm ops)
#pragma unroll
  for (int g = 0; g < 4; ++g) STAGE_G(0, g, 0);

  for (int kt = 0; kt < NT; ++kt) {
    const int cur = kt & 1, nxt = cur ^ 1;
    const bool pre = (kt + 1 < NT);
    const short* Ab = As[cur];
    const short* Bb = Bs[cur];
    bf16x8 af[8], bv[2];

    // ---- P0: drain tile kt (counted), read A.s0 + B.s0.n0, MFMA n-half 0 ----
    if (pre) {
      STAGE_G(nxt, 0, kt + 1);
      asm volatile("s_waitcnt vmcnt(2)" ::: "memory");  // tile kt resident; kt+1.g0 in flight
    } else {
      asm volatile("s_waitcnt vmcnt(0)" ::: "memory");
    }
    BAR();                 // RAW: all waves' tile-kt loads visible
    DSREAD_A(0);
    DSREAD_B(0, 0);
    WAIT_LGK();
    MFMA16(0);
    BAR();
    // ---- P1: read B.s0.n1 (A.s0 held in regs), stage g1 ----
    DSREAD_B(0, 1);
    if (pre) STAGE_G(nxt, 1, kt + 1);
    BAR();
    WAIT_LGK();
    MFMA16(1);
    BAR();
    // ---- P2: read A.s1 + B.s1.n0, stage g2 ----
    DSREAD_A(1);
    DSREAD_B(1, 0);
    if (pre) STAGE_G(nxt, 2, kt + 1);
    BAR();
    WAIT_LGK();
    MFMA16(0);
    BAR();
    // ---- P3: read B.s1.n1, stage g3 ----
    DSREAD_B(1, 1);
    if (pre) STAGE_G(nxt, 3, kt + 1);
    BAR();
    WAIT_LGK();
    MFMA16(1);
    BAR();
  }
#undef STAGE_G
#undef DSREAD_A
#undef DSREAD_B
#undef MFMA16
#undef WAIT_LGK
#undef BAR

  // epilogue: C/D layout col=lane&15, row=quad*4+reg (16x16 verified)
#pragma unroll
  for (int i = 0; i < 8; ++i) {
    const int r0 = bm + wr * 128 + i * 16 + quad * 4;
#pragma unroll
    for (int j = 0; j < 4; ++j) {
      const int col = bn + wc * 64 + j * 16 + l16;
#pragma unroll
      for (int r = 0; r < 4; ++r)
        Out[(size_t)(r0 + r) * NDIM + col] = acc[i][j][r];
    }
  }
}

// ---------------- fallback (fused, used only if ws too small) ----------------
constexpr int BKP = 72;
__global__ __launch_bounds__(256, 2)
void marlin_int4_gemm(const float* __restrict__ X, const int* __restrict__ Q,
                      const float* __restrict__ S, float* __restrict__ Out) {
  __shared__ short As[128 * BKP];
  __shared__ short Bs[128 * BKP];
  const int bm = blockIdx.x * 128, bn = blockIdx.y * 128;
  const int tid = threadIdx.x, lane = tid & 63, wave = tid >> 6;
  const int wm = (wave & 1) * 64, wn = (wave >> 1) * 64;
  const int quad = lane >> 4, l16 = lane & 15;
  const int nB = tid & 127, krB = (tid >> 7) * 32;
  f32x4 acc[4][4];
#pragma unroll
  for (int i = 0; i < 4; ++i)
#pragma unroll
    for (int j = 0; j < 4; ++j) acc[i][j] = (f32x4){0.f, 0.f, 0.f, 0.f};
  for (int kt = 0; kt < KDIM / 64; ++kt) {
    const int k0 = kt * 64;
    const float s = S[kt * NDIM + bn + nB];
    const float bias = -8.0f * s;
    __syncthreads();
#pragma unroll
    for (int i = 0; i < 8; ++i) {
      const int idx4 = tid + (i << 8);
      const int row = idx4 >> 4, col = (idx4 & 15) << 2;
      const float4 v = *(const float4*)(X + (size_t)(bm + row) * KDIM + k0 + col);
      ushort4 b;
      b.x = f2bf(v.x); b.y = f2bf(v.y); b.z = f2bf(v.z); b.w = f2bf(v.w);
      *(ushort4*)(&As[row * BKP + col]) = b;
    }
    unsigned short wb[32];
#pragma unroll
    for (int j = 0; j < 32; ++j) {
      const int qv = Q[(size_t)(k0 + krB + j) * NDIM + bn + nB];
      wb[j] = f2bf((float)qv * s + bias);
    }
    {
      short* brow = &Bs[nB * BKP + krB];
#pragma unroll
      for (int c = 0; c < 4; ++c) {
        bf16x8 v;
#pragma unroll
        for (int e = 0; e < 8; ++e) v[e] = (short)wb[c * 8 + e];
        *(bf16x8*)(brow + c * 8) = v;
      }
    }
    __syncthreads();
#pragma unroll
    for (int kk = 0; kk < 64; kk += 32) {
      bf16x8 af[4], bfr[4];
#pragma unroll
      for (int i = 0; i < 4; ++i)
        af[i] = *(const bf16x8*)&As[(wm + i * 16 + l16) * BKP + kk + quad * 8];
#pragma unroll
      for (int j = 0; j < 4; ++j)
        bfr[j] = *(const bf16x8*)&Bs[(wn + j * 16 + l16) * BKP + kk + quad * 8];
#pragma unroll
      for (int i = 0; i < 4; ++i)
#pragma unroll
        for (int j = 0; j < 4; ++j)
          acc[i][j] = __builtin_amdgcn_mfma_f32_16x16x32_bf16(af[i], bfr[j], acc[i][j], 0, 0, 0);
    }
  }
#pragma unroll
  for (int i = 0; i < 4; ++i) {
    const int r0 = bm + wm + i * 16 + quad * 4;
#pragma unroll
    for (int j = 0; j < 4; ++j) {
      const int col = bn + wn + j * 16 + l16;
#pragma unroll
      for (int r = 0; r < 4; ++r)
        Out[(size_t)(r0 + r) * NDIM + col] = acc[i][j][r];
    }
  }
}

extern "C" void kernel_launch(void* const* d_in, const int* in_sizes, int n_in,
                              void* d_out, int out_size, void* d_ws, size_t ws_size,
                              hipStream_t stream) {
  const float* X = (const float*)d_in[0];
  const int*   Q = (const int*)d_in[1];
  const float* S = (const float*)d_in[2];
  float* Out = (float*)d_out;

  const size_t xb_elems = (size_t)MDIM * KDIM;
  const size_t wt_elems = (size_t)NDIM * KDIM;
  const size_t need = (xb_elems + wt_elems) * sizeof(short);

  if (ws_size >= need) {
    short* Xb = (short*)d_ws;
    short* Wt = Xb + xb_elems;
    cvt_x_kernel<<<(int)(xb_elems / 8 / 256), 256, 0, stream>>>(X, Xb);
    dequant_w_kernel<<<dim3(KDIM / 256, NDIM / 128), 512, 0, stream>>>(Q, S, Wt);
    gemm_bf16tt<<<dim3(MDIM / 256, NDIM / 256), 512, 0, stream>>>(Xb, Wt, Out);
  } else {
    marlin_int4_gemm<<<dim3(MDIM / 128, NDIM / 128), 256, 0, stream>>>(X, Q, S, Out);
  }
}